// Round 12
// baseline (160.332 us; speedup 1.0000x reference)
//
#include <hip/hip_runtime.h>
#include <math.h>

#define NPIX 262144   // 512*512
#define NKER 15
#define PI_F 3.14159265358979323846f
#define HW 264        // half-plane row stride (float2): 257 used, padded to 8
#define CS 578        // wave scratch stride (float2): >= SK(511)=574
#define SK(n) ((n) + ((n) >> 3))   // skewed LDS index: <=4-way conflicts

__device__ __forceinline__ float2 cadd(float2 a, float2 b) { return make_float2(a.x + b.x, a.y + b.y); }
__device__ __forceinline__ float2 csub(float2 a, float2 b) { return make_float2(a.x - b.x, a.y - b.y); }
__device__ __forceinline__ float2 cmul(float2 a, float2 b) {
  return make_float2(a.x * b.x - a.y * b.y, a.x * b.y + a.y * b.x);
}

__device__ __forceinline__ void fft_roots(int lane, float2* w1, float2* wh) {
  float s, c;
  sincosf(-2.0f * PI_F * (float)lane / 512.0f, &s, &c);
  *w1 = make_float2(c, s);
  int h = lane & ~7;
  *wh = make_float2(__shfl(c, h, 64), __shfl(s, h, 64));
}

template <bool INV>
__device__ __forceinline__ void dft8(float2 a[8]) {
  const float R = 0.70710678118654752f;
  float2 t0 = cadd(a[0], a[4]), u0 = csub(a[0], a[4]);
  float2 t1 = cadd(a[1], a[5]), u1 = csub(a[1], a[5]);
  float2 t2 = cadd(a[2], a[6]), u2 = csub(a[2], a[6]);
  float2 t3 = cadd(a[3], a[7]), u3 = csub(a[3], a[7]);
  u1 = INV ? make_float2(R * (u1.x - u1.y), R * (u1.x + u1.y))
           : make_float2(R * (u1.x + u1.y), R * (u1.y - u1.x));
  u2 = INV ? make_float2(-u2.y, u2.x) : make_float2(u2.y, -u2.x);
  u3 = INV ? make_float2(-R * (u3.x + u3.y), R * (u3.x - u3.y))
           : make_float2(R * (u3.y - u3.x), -R * (u3.x + u3.y));
  float2 e0 = cadd(t0, t2), f0 = csub(t0, t2);
  float2 e1 = cadd(t1, t3), f1 = csub(t1, t3);
  f1 = INV ? make_float2(-f1.y, f1.x) : make_float2(f1.y, -f1.x);
  float2 g0 = cadd(u0, u2), h0 = csub(u0, u2);
  float2 g1 = cadd(u1, u3), h1 = csub(u1, u3);
  h1 = INV ? make_float2(-h1.y, h1.x) : make_float2(h1.y, -h1.x);
  a[0] = cadd(e0, e1); a[4] = csub(e0, e1);
  a[2] = cadd(f0, f1); a[6] = csub(f0, f1);
  a[1] = cadd(g0, g1); a[5] = csub(g0, g1);
  a[3] = cadd(h0, h1); a[7] = csub(h0, h1);
}

// 512-pt Stockham radix-8, one wave, 8 pts/thread, a[q] = point (lane+64q).
template <bool INV>
__device__ __forceinline__ void fft512_r8(float2 a[8], float2* buf, int lane,
                                          float2 w1, float2 wh) {
  float2 wa = INV ? make_float2(w1.x, -w1.y) : w1;
  float2 wb = INV ? make_float2(wh.x, -wh.y) : wh;
  dft8<INV>(a);
  {
    float2 tq = wa;
    a[1] = cmul(a[1], tq);
#pragma unroll
    for (int q = 2; q < 8; ++q) { tq = cmul(tq, wa); a[q] = cmul(a[q], tq); }
  }
#pragma unroll
  for (int q = 0; q < 8; ++q) buf[9 * lane + q] = a[q];
#pragma unroll
  for (int q = 0; q < 8; ++q) a[q] = buf[SK(lane + 64 * q)];
  dft8<INV>(a);
  {
    float2 tq = wb;
    a[1] = cmul(a[1], tq);
#pragma unroll
    for (int q = 2; q < 8; ++q) { tq = cmul(tq, wb); a[q] = cmul(a[q], tq); }
  }
  int h = lane & ~7;
  int b2 = 9 * h + (lane - h);
#pragma unroll
  for (int q = 0; q < 8; ++q) buf[b2 + 9 * q] = a[q];
#pragma unroll
  for (int q = 0; q < 8; ++q) a[q] = buf[SK(lane + 64 * q)];
  dft8<INV>(a);
}

// After packed FFT Z of (seqA + i seqB): write half-plane spectra of both.
__device__ __forceinline__ void split_store_halfplane(float2 a[8], float2* buf, int lane,
                                                      float2* d0, float2* d1) {
#pragma unroll
  for (int q = 0; q < 8; ++q) buf[SK(lane + 64 * q)] = a[q];
#pragma unroll
  for (int q = 0; q < 4; ++q) {
    int v = lane + 64 * q;
    int mir = (512 - v) & 511;
    float2 P = a[q];
    float2 Qc = buf[SK(mir)];
    d0[v] = make_float2(0.5f * (P.x + Qc.x), 0.5f * (P.y - Qc.y));
    d1[v] = make_float2(0.5f * (P.y + Qc.y), -0.5f * (P.x - Qc.x));
  }
  if (lane == 0) {
    float2 P = a[4];
    d0[256] = make_float2(P.x, 0.f);
    d1[256] = make_float2(P.y, 0.f);
  }
}

// Real-only variant: store just the first spectrum (imag input was zero).
__device__ __forceinline__ void split_store_lo(float2 a[8], float2* buf, int lane,
                                               float2* d0) {
#pragma unroll
  for (int q = 0; q < 8; ++q) buf[SK(lane + 64 * q)] = a[q];
#pragma unroll
  for (int q = 0; q < 4; ++q) {
    int v = lane + 64 * q;
    int mir = (512 - v) & 511;
    float2 P = a[q];
    float2 Qc = buf[SK(mir)];
    d0[v] = make_float2(0.5f * (P.x + Qc.x), 0.5f * (P.y - Qc.y));
  }
  if (lane == 0) d0[256] = make_float2(a[4].x, 0.f);
}

// ---- rows_all (512 threads, 8 waves) ----
// blocks 0..511: output row b of shifted kernels — stage Ks source row into the
//   shared pool (aliased with FFT scratch: krow is dead once FFT inputs are in
//   regs); row-sums -> partial; each wave does ONE packed k-pair FFT -> AkH.
//   LDS ~39 KB -> 4 blocks/CU (was 70 KB / 2 blocks).
// blocks 512..607: R2C row FFTs of x, 8 wave-jobs per block.
__global__ void rows_all(const float* __restrict__ Ks, const float* __restrict__ x,
                         float* __restrict__ partial, float2* __restrict__ AkH,
                         float2* __restrict__ AxH) {
  __shared__ float2 pool[8 * CS];      // 36992 B: krow (30720 B) then FFT scratch
  __shared__ float psum[480];          // 1920 B
  int t = threadIdx.x, wave = t >> 6, lane = t & 63;
  float2 w1, wh;
  fft_roots(lane, &w1, &wh);
  if (blockIdx.x < 512) {
    int b = blockIdx.x;              // output row
    int rs = (b + 256) & 511;        // fftshift row source
    const float2* src = (const float2*)Ks + (size_t)rs * 3840;
    float* krow = (float*)pool;
    for (int i = t; i < 3840; i += 512) pool[i] = src[i];
    __syncthreads();
    // row sums: 15 k x 32 y-groups of 16 (reads krow)
    if (t < 480) {
      int k = t >> 5, yg = t & 31;
      float s = 0.f;
      int base = yg * 16;
#pragma unroll
      for (int y = 0; y < 16; ++y) s += krow[(base + y) * NKER + k];
      psum[t] = s;
    }
    // FFT input regs (reads krow) — after this barrier krow is dead
    int k1 = 2 * wave, k2 = k1 + 1;     // wave 7: k2==15 -> real-only store
    float2 a[8];
#pragma unroll
    for (int q = 0; q < 8; ++q) {
      int ys = (lane + 64 * q + 256) & 511;   // fftshift col
      float re = krow[ys * NKER + k1];
      float im = (k2 < NKER) ? krow[ys * NKER + k2] : 0.f;
      a[q] = make_float2(re, im);
    }
    __syncthreads();                    // krow reads done; pool becomes scratch
    fft512_r8<false>(a, &pool[wave * CS], lane, w1, wh);
    float2* d0 = AkH + ((size_t)k1 * 512 + b) * HW;
    if (k2 < NKER) {
      float2* d1 = AkH + ((size_t)k2 * 512 + b) * HW;
      split_store_halfplane(a, &pool[wave * CS], lane, d0, d1);
    } else {
      split_store_lo(a, &pool[wave * CS], lane, d0);
    }
    // psum was fully written before the scratch barrier -> safe to reduce
    if (t < NKER) {
      float s = 0.f;
#pragma unroll
      for (int g = 0; g < 32; ++g) s += psum[(t << 5) + g];
      partial[b * 16 + t] = s;
    }
  } else {
    int job = (blockIdx.x - 512) * 8 + wave;   // 0..767
    int c = job >> 8;                // channel 0..2
    int rp = job & 255;              // row-pair 0..255
    int r0 = rp, r1 = rp + 256;
    float2 a[8];
#pragma unroll
    for (int q = 0; q < 8; ++q) {
      int y = lane + 64 * q;
      a[q] = make_float2(x[((size_t)r0 * 512 + y) * 3 + c],
                         x[((size_t)r1 * 512 + y) * 3 + c]);
    }
    fft512_r8<false>(a, &pool[wave * CS], lane, w1, wh);
    float2* d0 = AxH + ((size_t)c * 512 + r0) * HW;
    float2* d1 = AxH + ((size_t)c * 512 + r1) * HW;
    split_store_halfplane(a, &pool[wave * CS], lane, d0, d1);
  }
}

// ---- fused column pass (512 threads): stage AxH slab -> col FFT -> xh regs;
//      stage Ak slab -> fwd FFT -> *xh -> inv FFT -> store.
//      block (33, 0) = ksum_final; blocks (33, y>0) exit immediately. ----
__global__ void fused_cols(float2* __restrict__ AkH, const float2* __restrict__ AxH,
                           const int* __restrict__ c0, const float* __restrict__ partial,
                           float* __restrict__ sums) {
  __shared__ float2 buf[8 * CS];   // 36992 B (ksum block aliases it as red[])
  int t = threadIdx.x;
  if (blockIdx.x == 33) {
    if (blockIdx.y != 0) return;
    float* red = (float*)buf;
    int k = t & 15, g = t >> 4;        // 32 groups x 16 slots
    float acc = 0.f;
    for (int b = g; b < 512; b += 32) acc += partial[b * 16 + k];
    red[t] = acc;
    __syncthreads();
    if (t < 16) {
      float s = 0.f;
#pragma unroll
      for (int g2 = 0; g2 < 32; ++g2) s += red[g2 * 16 + t];
      sums[t] = s;
    }
    return;
  }
  int col0 = blockIdx.x * 8, k = blockIdx.y;
  int c = t >> 6, lane = t & 63;
  float2 w1, wh;
  fft_roots(lane, &w1, &wh);
  const float2* bx = AxH + (size_t)c0[k] * 512 * HW;
  float2* bk = AkH + (size_t)k * 512 * HW;
  // stage AxH slab (coalesced), col FFT -> xh in regs
#pragma unroll
  for (int u = 0; u < 8; ++u) {
    int idx = (u << 9) + t;
    int row = idx >> 3, cc = idx & 7;
    buf[cc * CS + SK(row)] = bx[(size_t)row * HW + col0 + cc];
  }
  __syncthreads();
  float2 xh[8];
#pragma unroll
  for (int q = 0; q < 8; ++q) xh[q] = buf[c * CS + SK(lane + 64 * q)];
  fft512_r8<false>(xh, &buf[c * CS], lane, w1, wh);
  __syncthreads();
  // stage Ak slab
#pragma unroll
  for (int u = 0; u < 8; ++u) {
    int idx = (u << 9) + t;
    int row = idx >> 3, cc = idx & 7;
    buf[cc * CS + SK(row)] = bk[(size_t)row * HW + col0 + cc];
  }
  __syncthreads();
  float2 a[8];
#pragma unroll
  for (int q = 0; q < 8; ++q) a[q] = buf[c * CS + SK(lane + 64 * q)];
  fft512_r8<false>(a, &buf[c * CS], lane, w1, wh);
#pragma unroll
  for (int q = 0; q < 8; ++q) a[q] = cmul(a[q], xh[q]);
  fft512_r8<true>(a, &buf[c * CS], lane, w1, wh);
#pragma unroll
  for (int q = 0; q < 8; ++q) buf[c * CS + SK(lane + 64 * q)] = a[q];
  __syncthreads();
#pragma unroll
  for (int u = 0; u < 8; ++u) {
    int idx = (u << 9) + t;
    int row = idx >> 3, cc = idx & 7;
    bk[(size_t)row * HW + col0 + cc] = buf[cc * CS + SK(row)];
  }
}

// ---- C2R inverse row FFT + deferred norm + growth + combine -> Hs ----
// 512 threads, 8 waves, slot = wave; accumulation via LDS float atomics
// (exactly 8 adds per address). LDS ~44 KB -> 3 blocks/CU (was 62 KB / 2).
__global__ void irows_growth_combine(const float2* __restrict__ AkH,
                                     const float* __restrict__ sums,
                                     const float* __restrict__ m, const float* __restrict__ s,
                                     const float* __restrict__ h, const float* __restrict__ w,
                                     float* __restrict__ Hs) {
  __shared__ float2 scr[8][CS];        // 36992 B
  __shared__ float accS[3][512];       // 6144 B
  __shared__ float mk[16], isk[16], hk[16], wk[16][3], sck[16];
  int t = threadIdx.x, wave = t >> 6, lane = t & 63;
  int row = blockIdx.x;
  accS[0][t] = 0.f; accS[1][t] = 0.f; accS[2][t] = 0.f;
  if (t < NKER) {
    mk[t] = m[t]; isk[t] = 1.0f / s[t]; hk[t] = h[t];
    sck[t] = 1.0f / (sums[t] * 262144.0f);
    wk[t][0] = w[t * 3 + 0]; wk[t][1] = w[t * 3 + 1]; wk[t][2] = w[t * 3 + 2];
  }
  __syncthreads();
  float2 w1, wh;
  fft_roots(lane, &w1, &wh);
  float acc[3][8];
#pragma unroll
  for (int cc = 0; cc < 3; ++cc)
#pragma unroll
    for (int q = 0; q < 8; ++q) acc[cc][q] = 0.f;
  {
    int k1 = 2 * wave, k2 = 2 * wave + 1;
    bool dual = (k2 < NKER);
    const float2* p1 = AkH + ((size_t)k1 * 512 + row) * HW;
    const float2* p2 = AkH + ((size_t)(dual ? k2 : k1) * 512 + row) * HW;
    float2 a[8];
#pragma unroll
    for (int q = 0; q < 8; ++q) {
      int v = lane + 64 * q;
      if (v <= 256) {
        float2 A1 = p1[v];
        float2 A2 = dual ? p2[v] : make_float2(0.f, 0.f);
        a[q] = make_float2(A1.x - A2.y, A1.y + A2.x);          // A1 + i*A2
      } else {
        int mi = 512 - v;
        float2 A1 = p1[mi];
        float2 A2 = dual ? p2[mi] : make_float2(0.f, 0.f);
        a[q] = make_float2(A1.x + A2.y, -A1.y + A2.x);         // conj(A1) + i*conj(A2)
      }
    }
    fft512_r8<true>(a, &scr[wave][0], lane, w1, wh);
    float m1 = mk[k1], i1 = isk[k1], h1 = hk[k1], s1 = sck[k1];
    float w10 = wk[k1][0], w11 = wk[k1][1], w12 = wk[k1][2];
#pragma unroll
    for (int q = 0; q < 8; ++q) {
      float tt = (a[q].x * s1 - m1) * i1;
      float g = (expf(-0.5f * tt * tt) * 2.0f - 1.0f) * h1;
      acc[0][q] += g * w10; acc[1][q] += g * w11; acc[2][q] += g * w12;
    }
    if (dual) {
      float m2 = mk[k2], i2 = isk[k2], h2 = hk[k2], s2 = sck[k2];
      float w20 = wk[k2][0], w21 = wk[k2][1], w22 = wk[k2][2];
#pragma unroll
      for (int q = 0; q < 8; ++q) {
        float tt = (a[q].y * s2 - m2) * i2;
        float g = (expf(-0.5f * tt * tt) * 2.0f - 1.0f) * h2;
        acc[0][q] += g * w20; acc[1][q] += g * w21; acc[2][q] += g * w22;
      }
    }
  }
#pragma unroll
  for (int cc = 0; cc < 3; ++cc)
#pragma unroll
    for (int q = 0; q < 8; ++q)
      atomicAdd(&accS[cc][lane + 64 * q], acc[cc][q]);
  __syncthreads();
#pragma unroll
  for (int cc = 0; cc < 3; ++cc)
    Hs[(size_t)cc * NPIX + (size_t)row * 512 + t] = accS[cc][t];
}

// ---- fused flow + reintegrate: 16x16 output tile, mu over 20x20 halo in LDS ----
__global__ void flow_reint(const float* __restrict__ x, const float* __restrict__ Hs,
                           float* __restrict__ out) {
  __shared__ float muT[20 * 20 * 6];
  __shared__ float xT[20 * 20 * 3];
  int ox = (blockIdx.x >> 5) << 4;
  int oy = (blockIdx.x & 31) << 4;
  for (int i = threadIdx.x; i < 400; i += 256) {
    int hi = i / 20, hj = i % 20;
    int qx = (ox - 2 + hi) & 511, qy = (oy - 2 + hj) & 511;
    float syH0 = 0.f, syH1 = 0.f, syH2 = 0.f;
    float sxH0 = 0.f, sxH1 = 0.f, sxH2 = 0.f;
    float syX = 0.f, sxX = 0.f;
#pragma unroll
    for (int di = -1; di <= 1; ++di) {
#pragma unroll
      for (int dj = -1; dj <= 1; ++dj) {
        if (di == 0 && dj == 0) continue;
        int xi = qx + di, yj = qy + dj;
        if ((unsigned)xi >= 512u || (unsigned)yj >= 512u) continue;  // zero pad
        float wy = (float)di * ((dj == 0) ? 2.f : 1.f);
        float wx = (float)dj * ((di == 0) ? 2.f : 1.f);
        int q = (xi << 9) | yj;
        float h0 = Hs[q], h1 = Hs[NPIX + q], h2 = Hs[2 * NPIX + q];
        syH0 += wy * h0; syH1 += wy * h1; syH2 += wy * h2;
        sxH0 += wx * h0; sxH1 += wx * h1; sxH2 += wx * h2;
        float xs = x[(size_t)q * 3 + 0] + x[(size_t)q * 3 + 1] + x[(size_t)q * 3 + 2];
        syX += wy * xs; sxX += wx * xs;
      }
    }
    int qp = (qx << 9) | qy;
    float cxq = (float)qx + 0.5f, cyq = (float)qy + 0.5f;
    float syH[3] = {syH0, syH1, syH2};
    float sxH[3] = {sxH0, sxH1, sxH2};
    int b6 = i * 6, b3 = i * 3;
#pragma unroll
    for (int c = 0; c < 3; ++c) {
      float xc = x[(size_t)qp * 3 + c];
      xT[b3 + c] = xc;
      float tt = xc * 0.5f;
      float alpha = fminf(tt * tt, 1.0f);
      float F0 = syH[c] * (1.f - alpha) - syX * alpha;
      float F1 = sxH[c] * (1.f - alpha) - sxX * alpha;
      float m0 = cxq + fminf(fmaxf(0.2f * F0, -1.05f), 1.05f);
      float m1 = cyq + fminf(fmaxf(0.2f * F1, -1.05f), 1.05f);
      muT[b6 + c]     = fminf(fmaxf(m0, 0.95f), 511.05f);
      muT[b6 + 3 + c] = fminf(fmaxf(m1, 0.95f), 511.05f);
    }
  }
  __syncthreads();
  int o = threadIdx.x;
  int lx = o >> 4, ly = o & 15;
  int px_ = ox + lx, py_ = oy + ly;
  float cx = (float)px_ + 0.5f, cy = (float)py_ + 0.5f;
  float a0 = 0.f, a1 = 0.f, a2 = 0.f;
#pragma unroll
  for (int dx = -2; dx <= 2; ++dx) {
    int hi = lx + 2 - dx;
#pragma unroll
    for (int dy = -2; dy <= 2; ++dy) {
      int hj = ly + 2 - dy;
      int b6 = (hi * 20 + hj) * 6, b3 = (hi * 20 + hj) * 3;
      float wv;
      wv = fminf(fmaxf(1.45f - fabsf(cx - muT[b6 + 0]), 0.f), 1.f) *
           fminf(fmaxf(1.45f - fabsf(cy - muT[b6 + 3]), 0.f), 1.f);
      a0 += xT[b3 + 0] * wv;
      wv = fminf(fmaxf(1.45f - fabsf(cx - muT[b6 + 1]), 0.f), 1.f) *
           fminf(fmaxf(1.45f - fabsf(cy - muT[b6 + 4]), 0.f), 1.f);
      a1 += xT[b3 + 1] * wv;
      wv = fminf(fmaxf(1.45f - fabsf(cx - muT[b6 + 2]), 0.f), 1.f) *
           fminf(fmaxf(1.45f - fabsf(cy - muT[b6 + 5]), 0.f), 1.f);
      a2 += xT[b3 + 2] * wv;
    }
  }
  const float inv_area = 0.27700831f;  // 1/(4*0.95^2)
  size_t p = (size_t)((px_ << 9) | py_);
  out[p * 3 + 0] = a0 * inv_area;
  out[p * 3 + 1] = a1 * inv_area;
  out[p * 3 + 2] = a2 * inv_area;
}

extern "C" void kernel_launch(void* const* d_in, const int* in_sizes, int n_in,
                              void* d_out, int out_size, void* d_ws, size_t ws_size,
                              hipStream_t stream) {
  const float* x    = (const float*)d_in[0];
  const float* Ks   = (const float*)d_in[1];
  const float* m    = (const float*)d_in[2];
  const float* s    = (const float*)d_in[3];
  const float* h    = (const float*)d_in[4];
  const float* w_c1 = (const float*)d_in[5];
  const int*   c0   = (const int*)d_in[6];
  float* out = (float*)d_out;

  char* ws = (char*)d_ws;
  size_t off = 0;
  float* sums    = (float*)(ws + off); off += 1024;
  float* partial = (float*)(ws + off); off += 512 * 16 * 4;
  float2* AxH  = (float2*)(ws + off); off += (size_t)3 * 512 * HW * 8;    // 3.2 MB
  float2* AkH  = (float2*)(ws + off); off += (size_t)16 * 512 * HW * 8;   // 17.3 MB (plane 15 unused)
  float*  Hs   = (float*)(ws + off);  off += (size_t)3 * NPIX * 4;        // 3 MB

  rows_all<<<608, 512, 0, stream>>>(Ks, x, partial, AkH, AxH);
  fused_cols<<<dim3(34, NKER), 512, 0, stream>>>(AkH, AxH, c0, partial, sums);
  irows_growth_combine<<<512, 512, 0, stream>>>(AkH, sums, m, s, h, w_c1, Hs);
  flow_reint<<<1024, 256, 0, stream>>>(x, Hs, out);
}

// Round 13
// 131.061 us; speedup vs baseline: 1.2233x; 1.2233x over previous
//
#include <hip/hip_runtime.h>
#include <math.h>

#define NPIX 262144   // 512*512
#define NKER 15
#define PI_F 3.14159265358979323846f
#define HW 264        // half-plane row stride (float2): 257 used, padded to 8
#define CS 578        // wave scratch stride (float2): >= SK(511)=574
#define SK(n) ((n) + ((n) >> 3))   // skewed LDS index: <=4-way conflicts

__device__ __forceinline__ float2 cadd(float2 a, float2 b) { return make_float2(a.x + b.x, a.y + b.y); }
__device__ __forceinline__ float2 csub(float2 a, float2 b) { return make_float2(a.x - b.x, a.y - b.y); }
__device__ __forceinline__ float2 cmul(float2 a, float2 b) {
  return make_float2(a.x * b.x - a.y * b.y, a.x * b.y + a.y * b.x);
}

__device__ __forceinline__ void fft_roots(int lane, float2* w1, float2* wh) {
  float s, c;
  sincosf(-2.0f * PI_F * (float)lane / 512.0f, &s, &c);
  *w1 = make_float2(c, s);
  int h = lane & ~7;
  *wh = make_float2(__shfl(c, h, 64), __shfl(s, h, 64));
}

template <bool INV>
__device__ __forceinline__ void dft8(float2 a[8]) {
  const float R = 0.70710678118654752f;
  float2 t0 = cadd(a[0], a[4]), u0 = csub(a[0], a[4]);
  float2 t1 = cadd(a[1], a[5]), u1 = csub(a[1], a[5]);
  float2 t2 = cadd(a[2], a[6]), u2 = csub(a[2], a[6]);
  float2 t3 = cadd(a[3], a[7]), u3 = csub(a[3], a[7]);
  u1 = INV ? make_float2(R * (u1.x - u1.y), R * (u1.x + u1.y))
           : make_float2(R * (u1.x + u1.y), R * (u1.y - u1.x));
  u2 = INV ? make_float2(-u2.y, u2.x) : make_float2(u2.y, -u2.x);
  u3 = INV ? make_float2(-R * (u3.x + u3.y), R * (u3.x - u3.y))
           : make_float2(R * (u3.y - u3.x), -R * (u3.x + u3.y));
  float2 e0 = cadd(t0, t2), f0 = csub(t0, t2);
  float2 e1 = cadd(t1, t3), f1 = csub(t1, t3);
  f1 = INV ? make_float2(-f1.y, f1.x) : make_float2(f1.y, -f1.x);
  float2 g0 = cadd(u0, u2), h0 = csub(u0, u2);
  float2 g1 = cadd(u1, u3), h1 = csub(u1, u3);
  h1 = INV ? make_float2(-h1.y, h1.x) : make_float2(h1.y, -h1.x);
  a[0] = cadd(e0, e1); a[4] = csub(e0, e1);
  a[2] = cadd(f0, f1); a[6] = csub(f0, f1);
  a[1] = cadd(g0, g1); a[5] = csub(g0, g1);
  a[3] = cadd(h0, h1); a[7] = csub(h0, h1);
}

// 512-pt Stockham radix-8, one wave, 8 pts/thread, a[q] = point (lane+64q).
template <bool INV>
__device__ __forceinline__ void fft512_r8(float2 a[8], float2* buf, int lane,
                                          float2 w1, float2 wh) {
  float2 wa = INV ? make_float2(w1.x, -w1.y) : w1;
  float2 wb = INV ? make_float2(wh.x, -wh.y) : wh;
  dft8<INV>(a);
  {
    float2 tq = wa;
    a[1] = cmul(a[1], tq);
#pragma unroll
    for (int q = 2; q < 8; ++q) { tq = cmul(tq, wa); a[q] = cmul(a[q], tq); }
  }
#pragma unroll
  for (int q = 0; q < 8; ++q) buf[9 * lane + q] = a[q];
#pragma unroll
  for (int q = 0; q < 8; ++q) a[q] = buf[SK(lane + 64 * q)];
  dft8<INV>(a);
  {
    float2 tq = wb;
    a[1] = cmul(a[1], tq);
#pragma unroll
    for (int q = 2; q < 8; ++q) { tq = cmul(tq, wb); a[q] = cmul(a[q], tq); }
  }
  int h = lane & ~7;
  int b2 = 9 * h + (lane - h);
#pragma unroll
  for (int q = 0; q < 8; ++q) buf[b2 + 9 * q] = a[q];
#pragma unroll
  for (int q = 0; q < 8; ++q) a[q] = buf[SK(lane + 64 * q)];
  dft8<INV>(a);
}

// After packed FFT Z of (seqA + i seqB): write half-plane spectra of both.
__device__ __forceinline__ void split_store_halfplane(float2 a[8], float2* buf, int lane,
                                                      float2* d0, float2* d1) {
#pragma unroll
  for (int q = 0; q < 8; ++q) buf[SK(lane + 64 * q)] = a[q];
#pragma unroll
  for (int q = 0; q < 4; ++q) {
    int v = lane + 64 * q;
    int mir = (512 - v) & 511;
    float2 P = a[q];
    float2 Qc = buf[SK(mir)];
    float2 Q = make_float2(Qc.x, -Qc.y);
    d0[v] = make_float2(0.5f * (P.x + Q.x), 0.5f * (P.y + Q.y));
    d1[v] = make_float2(0.5f * (P.y - Q.y), -0.5f * (P.x - Q.x));
  }
  if (lane == 0) {
    float2 P = a[4];
    d0[256] = make_float2(P.x, 0.f);
    d1[256] = make_float2(P.y, 0.f);
  }
}

// ---- rows_all (512 threads, 8 waves) ----
// blocks 0..511: output row b of shifted kernels — stage Ks source row
//   (b+256)&511 into LDS; row-sums -> partial; 8 waves each do ONE packed
//   k-pair FFT (slot=wave; plane 15 = dummy) -> AkH (UNSCALED).
// blocks 512..607: R2C row FFTs of x, 8 wave-jobs per block (3ch x 256 pairs).
__global__ void rows_all(const float* __restrict__ Ks, const float* __restrict__ x,
                         float* __restrict__ partial, float2* __restrict__ AkH,
                         float2* __restrict__ AxH) {
  __shared__ float krow[512 * NKER];   // 30720 B
  __shared__ float2 scr[8][CS];        // 36992 B
  __shared__ float psum[480];          // 1920 B
  int t = threadIdx.x, wave = t >> 6, lane = t & 63;
  float2 w1, wh;
  fft_roots(lane, &w1, &wh);
  if (blockIdx.x < 512) {
    int b = blockIdx.x;              // output row
    int rs = (b + 256) & 511;        // fftshift row source
    const float2* src = (const float2*)Ks + (size_t)rs * 3840;
    float2* kr2 = (float2*)krow;
    for (int i = t; i < 3840; i += 512) kr2[i] = src[i];
    __syncthreads();
    // row sums: 15 k x 32 y-groups of 16  (512 threads cover all 480 slots)
    if (t < 480) {
      int k = t >> 5, yg = t & 31;
      float s = 0.f;
      int base = yg * 16;
#pragma unroll
      for (int y = 0; y < 16; ++y) s += krow[(base + y) * NKER + k];
      psum[t] = s;
    }
    // one packed k-pair FFT per wave: slot = wave (0..7)
    {
      int k1 = 2 * wave, k2 = k1 + 1;     // k2==15 -> dummy plane
      float2 a[8];
#pragma unroll
      for (int q = 0; q < 8; ++q) {
        int ys = (lane + 64 * q + 256) & 511;   // fftshift col
        float re = krow[ys * NKER + k1];
        float im = (k2 < NKER) ? krow[ys * NKER + k2] : 0.f;
        a[q] = make_float2(re, im);
      }
      fft512_r8<false>(a, &scr[wave][0], lane, w1, wh);
      float2* d0 = AkH + ((size_t)k1 * 512 + b) * HW;
      float2* d1 = AkH + ((size_t)k2 * 512 + b) * HW;   // plane 15 = scratch
      split_store_halfplane(a, &scr[wave][0], lane, d0, d1);
    }
    __syncthreads();
    if (t < NKER) {
      float s = 0.f;
#pragma unroll
      for (int g = 0; g < 32; ++g) s += psum[(t << 5) + g];
      partial[b * 16 + t] = s;
    }
  } else {
    int job = (blockIdx.x - 512) * 8 + wave;   // 0..767
    int c = job >> 8;                // channel 0..2
    int rp = job & 255;              // row-pair 0..255
    int r0 = rp, r1 = rp + 256;
    float2 a[8];
#pragma unroll
    for (int q = 0; q < 8; ++q) {
      int y = lane + 64 * q;
      a[q] = make_float2(x[((size_t)r0 * 512 + y) * 3 + c],
                         x[((size_t)r1 * 512 + y) * 3 + c]);
    }
    fft512_r8<false>(a, &scr[wave][0], lane, w1, wh);
    float2* d0 = AxH + ((size_t)c * 512 + r0) * HW;
    float2* d1 = AxH + ((size_t)c * 512 + r1) * HW;
    split_store_halfplane(a, &scr[wave][0], lane, d0, d1);
  }
}

// ---- fused column pass (512 threads): stage AxH slab -> col FFT -> xh regs;
//      stage Ak slab -> fwd FFT -> *xh -> inv FFT -> store.
//      block (33, 0) = ksum_final; blocks (33, y>0) exit immediately. ----
__global__ void fused_cols(float2* __restrict__ AkH, const float2* __restrict__ AxH,
                           const int* __restrict__ c0, const float* __restrict__ partial,
                           float* __restrict__ sums) {
  __shared__ float2 buf[8 * CS];   // 36992 B
  __shared__ float red[512];
  int t = threadIdx.x;
  if (blockIdx.x == 33) {
    if (blockIdx.y != 0) return;
    int k = t & 15, g = t >> 4;        // 32 groups x 16 slots
    float acc = 0.f;
    for (int b = g; b < 512; b += 32) acc += partial[b * 16 + k];
    red[t] = acc;
    __syncthreads();
    if (t < 16) {
      float s = 0.f;
#pragma unroll
      for (int g2 = 0; g2 < 32; ++g2) s += red[g2 * 16 + t];
      sums[t] = s;
    }
    return;
  }
  int col0 = blockIdx.x * 8, k = blockIdx.y;
  int c = t >> 6, lane = t & 63;
  float2 w1, wh;
  fft_roots(lane, &w1, &wh);
  const float2* bx = AxH + (size_t)c0[k] * 512 * HW;
  float2* bk = AkH + (size_t)k * 512 * HW;
  // stage AxH slab (coalesced), col FFT -> xh in regs
#pragma unroll
  for (int u = 0; u < 8; ++u) {
    int idx = (u << 9) + t;
    int row = idx >> 3, cc = idx & 7;
    buf[cc * CS + SK(row)] = bx[(size_t)row * HW + col0 + cc];
  }
  __syncthreads();
  float2 xh[8];
#pragma unroll
  for (int q = 0; q < 8; ++q) xh[q] = buf[c * CS + SK(lane + 64 * q)];
  fft512_r8<false>(xh, &buf[c * CS], lane, w1, wh);
  __syncthreads();
  // stage Ak slab
#pragma unroll
  for (int u = 0; u < 8; ++u) {
    int idx = (u << 9) + t;
    int row = idx >> 3, cc = idx & 7;
    buf[cc * CS + SK(row)] = bk[(size_t)row * HW + col0 + cc];
  }
  __syncthreads();
  float2 a[8];
#pragma unroll
  for (int q = 0; q < 8; ++q) a[q] = buf[c * CS + SK(lane + 64 * q)];
  fft512_r8<false>(a, &buf[c * CS], lane, w1, wh);
#pragma unroll
  for (int q = 0; q < 8; ++q) a[q] = cmul(a[q], xh[q]);
  fft512_r8<true>(a, &buf[c * CS], lane, w1, wh);
#pragma unroll
  for (int q = 0; q < 8; ++q) buf[c * CS + SK(lane + 64 * q)] = a[q];
  __syncthreads();
#pragma unroll
  for (int u = 0; u < 8; ++u) {
    int idx = (u << 9) + t;
    int row = idx >> 3, cc = idx & 7;
    bk[(size_t)row * HW + col0 + cc] = buf[cc * CS + SK(row)];
  }
}

// ---- C2R inverse row FFT + deferred norm + growth + combine -> Hs ----
// 512 threads: 8 waves, slot = wave; two-step accL accumulation (4 planes).
__global__ void irows_growth_combine(const float2* __restrict__ AkH,
                                     const float* __restrict__ sums,
                                     const float* __restrict__ m, const float* __restrict__ s,
                                     const float* __restrict__ h, const float* __restrict__ w,
                                     float* __restrict__ Hs) {
  __shared__ float2 scr[8][CS];        // 36992 B
  __shared__ float accL[4][3][512];    // 24576 B
  __shared__ float mk[16], isk[16], hk[16], wk[16][3], sck[16];
  int t = threadIdx.x, wave = t >> 6, lane = t & 63;
  int row = blockIdx.x;
  if (t < NKER) {
    mk[t] = m[t]; isk[t] = 1.0f / s[t]; hk[t] = h[t];
    sck[t] = 1.0f / (sums[t] * 262144.0f);
    wk[t][0] = w[t * 3 + 0]; wk[t][1] = w[t * 3 + 1]; wk[t][2] = w[t * 3 + 2];
  }
  __syncthreads();
  float2 w1, wh;
  fft_roots(lane, &w1, &wh);
  float acc[3][8];
#pragma unroll
  for (int cc = 0; cc < 3; ++cc)
#pragma unroll
    for (int q = 0; q < 8; ++q) acc[cc][q] = 0.f;
  {
    int slot = wave;
    int k1 = 2 * slot, k2 = 2 * slot + 1;
    bool dual = (k2 < NKER);
    const float2* p1 = AkH + ((size_t)k1 * 512 + row) * HW;
    const float2* p2 = AkH + ((size_t)(dual ? k2 : k1) * 512 + row) * HW;
    float2 a[8];
#pragma unroll
    for (int q = 0; q < 8; ++q) {
      int v = lane + 64 * q;
      if (v <= 256) {
        float2 A1 = p1[v];
        float2 A2 = dual ? p2[v] : make_float2(0.f, 0.f);
        a[q] = make_float2(A1.x - A2.y, A1.y + A2.x);          // A1 + i*A2
      } else {
        int mi = 512 - v;
        float2 A1 = p1[mi];
        float2 A2 = dual ? p2[mi] : make_float2(0.f, 0.f);
        a[q] = make_float2(A1.x + A2.y, -A1.y + A2.x);         // conj(A1) + i*conj(A2)
      }
    }
    fft512_r8<true>(a, &scr[wave][0], lane, w1, wh);
    float m1 = mk[k1], i1 = isk[k1], h1 = hk[k1], s1 = sck[k1];
    float w10 = wk[k1][0], w11 = wk[k1][1], w12 = wk[k1][2];
#pragma unroll
    for (int q = 0; q < 8; ++q) {
      float tt = (a[q].x * s1 - m1) * i1;
      float g = (expf(-0.5f * tt * tt) * 2.0f - 1.0f) * h1;
      acc[0][q] += g * w10; acc[1][q] += g * w11; acc[2][q] += g * w12;
    }
    if (dual) {
      float m2 = mk[k2], i2 = isk[k2], h2 = hk[k2], s2 = sck[k2];
      float w20 = wk[k2][0], w21 = wk[k2][1], w22 = wk[k2][2];
#pragma unroll
      for (int q = 0; q < 8; ++q) {
        float tt = (a[q].y * s2 - m2) * i2;
        float g = (expf(-0.5f * tt * tt) * 2.0f - 1.0f) * h2;
        acc[0][q] += g * w20; acc[1][q] += g * w21; acc[2][q] += g * w22;
      }
    }
  }
  // two-step accumulation into 4 planes (waves 0-3 write, waves 4-7 add)
  if (wave < 4) {
#pragma unroll
    for (int cc = 0; cc < 3; ++cc)
#pragma unroll
      for (int q = 0; q < 8; ++q) accL[wave][cc][lane + 64 * q] = acc[cc][q];
  }
  __syncthreads();
  if (wave >= 4) {
#pragma unroll
    for (int cc = 0; cc < 3; ++cc)
#pragma unroll
      for (int q = 0; q < 8; ++q) accL[wave - 4][cc][lane + 64 * q] += acc[cc][q];
  }
  __syncthreads();
#pragma unroll
  for (int cc = 0; cc < 3; ++cc) {
    float v = accL[0][cc][t] + accL[1][cc][t] + accL[2][cc][t] + accL[3][cc][t];
    Hs[(size_t)cc * NPIX + (size_t)row * 512 + t] = v;
  }
}

// ---- fused flow + reintegrate: 16x16 output tile, mu over 20x20 halo in LDS ----
__global__ void flow_reint(const float* __restrict__ x, const float* __restrict__ Hs,
                           float* __restrict__ out) {
  __shared__ float muT[20 * 20 * 6];
  __shared__ float xT[20 * 20 * 3];
  int ox = (blockIdx.x >> 5) << 4;
  int oy = (blockIdx.x & 31) << 4;
  for (int i = threadIdx.x; i < 400; i += 256) {
    int hi = i / 20, hj = i % 20;
    int qx = (ox - 2 + hi) & 511, qy = (oy - 2 + hj) & 511;
    float syH0 = 0.f, syH1 = 0.f, syH2 = 0.f;
    float sxH0 = 0.f, sxH1 = 0.f, sxH2 = 0.f;
    float syX = 0.f, sxX = 0.f;
#pragma unroll
    for (int di = -1; di <= 1; ++di) {
#pragma unroll
      for (int dj = -1; dj <= 1; ++dj) {
        if (di == 0 && dj == 0) continue;
        int xi = qx + di, yj = qy + dj;
        if ((unsigned)xi >= 512u || (unsigned)yj >= 512u) continue;  // zero pad
        float wy = (float)di * ((dj == 0) ? 2.f : 1.f);
        float wx = (float)dj * ((di == 0) ? 2.f : 1.f);
        int q = (xi << 9) | yj;
        float h0 = Hs[q], h1 = Hs[NPIX + q], h2 = Hs[2 * NPIX + q];
        syH0 += wy * h0; syH1 += wy * h1; syH2 += wy * h2;
        sxH0 += wx * h0; sxH1 += wx * h1; sxH2 += wx * h2;
        float xs = x[(size_t)q * 3 + 0] + x[(size_t)q * 3 + 1] + x[(size_t)q * 3 + 2];
        syX += wy * xs; sxX += wx * xs;
      }
    }
    int qp = (qx << 9) | qy;
    float cxq = (float)qx + 0.5f, cyq = (float)qy + 0.5f;
    float syH[3] = {syH0, syH1, syH2};
    float sxH[3] = {sxH0, sxH1, sxH2};
    int b6 = i * 6, b3 = i * 3;
#pragma unroll
    for (int c = 0; c < 3; ++c) {
      float xc = x[(size_t)qp * 3 + c];
      xT[b3 + c] = xc;
      float tt = xc * 0.5f;
      float alpha = fminf(tt * tt, 1.0f);
      float F0 = syH[c] * (1.f - alpha) - syX * alpha;
      float F1 = sxH[c] * (1.f - alpha) - sxX * alpha;
      float m0 = cxq + fminf(fmaxf(0.2f * F0, -1.05f), 1.05f);
      float m1 = cyq + fminf(fmaxf(0.2f * F1, -1.05f), 1.05f);
      muT[b6 + c]     = fminf(fmaxf(m0, 0.95f), 511.05f);
      muT[b6 + 3 + c] = fminf(fmaxf(m1, 0.95f), 511.05f);
    }
  }
  __syncthreads();
  int o = threadIdx.x;
  int lx = o >> 4, ly = o & 15;
  int px_ = ox + lx, py_ = oy + ly;
  float cx = (float)px_ + 0.5f, cy = (float)py_ + 0.5f;
  float a0 = 0.f, a1 = 0.f, a2 = 0.f;
#pragma unroll
  for (int dx = -2; dx <= 2; ++dx) {
    int hi = lx + 2 - dx;
#pragma unroll
    for (int dy = -2; dy <= 2; ++dy) {
      int hj = ly + 2 - dy;
      int b6 = (hi * 20 + hj) * 6, b3 = (hi * 20 + hj) * 3;
      float wv;
      wv = fminf(fmaxf(1.45f - fabsf(cx - muT[b6 + 0]), 0.f), 1.f) *
           fminf(fmaxf(1.45f - fabsf(cy - muT[b6 + 3]), 0.f), 1.f);
      a0 += xT[b3 + 0] * wv;
      wv = fminf(fmaxf(1.45f - fabsf(cx - muT[b6 + 1]), 0.f), 1.f) *
           fminf(fmaxf(1.45f - fabsf(cy - muT[b6 + 4]), 0.f), 1.f);
      a1 += xT[b3 + 1] * wv;
      wv = fminf(fmaxf(1.45f - fabsf(cx - muT[b6 + 2]), 0.f), 1.f) *
           fminf(fmaxf(1.45f - fabsf(cy - muT[b6 + 5]), 0.f), 1.f);
      a2 += xT[b3 + 2] * wv;
    }
  }
  const float inv_area = 0.27700831f;  // 1/(4*0.95^2)
  size_t p = (size_t)((px_ << 9) | py_);
  out[p * 3 + 0] = a0 * inv_area;
  out[p * 3 + 1] = a1 * inv_area;
  out[p * 3 + 2] = a2 * inv_area;
}

extern "C" void kernel_launch(void* const* d_in, const int* in_sizes, int n_in,
                              void* d_out, int out_size, void* d_ws, size_t ws_size,
                              hipStream_t stream) {
  const float* x    = (const float*)d_in[0];
  const float* Ks   = (const float*)d_in[1];
  const float* m    = (const float*)d_in[2];
  const float* s    = (const float*)d_in[3];
  const float* h    = (const float*)d_in[4];
  const float* w_c1 = (const float*)d_in[5];
  const int*   c0   = (const int*)d_in[6];
  float* out = (float*)d_out;

  char* ws = (char*)d_ws;
  size_t off = 0;
  float* sums    = (float*)(ws + off); off += 1024;
  float* partial = (float*)(ws + off); off += 512 * 16 * 4;
  float2* AxH  = (float2*)(ws + off); off += (size_t)3 * 512 * HW * 8;    // 3.2 MB
  float2* AkH  = (float2*)(ws + off); off += (size_t)16 * 512 * HW * 8;   // 17.3 MB (plane 15 dummy)
  float*  Hs   = (float*)(ws + off);  off += (size_t)3 * NPIX * 4;        // 3 MB

  rows_all<<<608, 512, 0, stream>>>(Ks, x, partial, AkH, AxH);
  fused_cols<<<dim3(34, NKER), 512, 0, stream>>>(AkH, AxH, c0, partial, sums);
  irows_growth_combine<<<512, 512, 0, stream>>>(AkH, sums, m, s, h, w_c1, Hs);
  flow_reint<<<1024, 256, 0, stream>>>(x, Hs, out);
}